// Round 5
// baseline (441.721 us; speedup 1.0000x reference)
//
#include <hip/hip_runtime.h>

// Problem: B=16, C=1, H=2048, W=2048 fp32.
// out = a0*x + a1*(left+right) + a2*(up+down)   (replicate-padded 5-pt stencil)
//     + w0 + w1*x + w2*x^2 + w3*x^3             (Horner, CONST=0)
//
// v6 strategy (v2-v5 post-mortem: traffic, MLP, neighbor machinery, NT all
// ~null; per-wave lifetime ~65K cycles vs ~3K critical path => deep queueing.
// m13 copy hits 6.29 TB/s with 32 shallow waves/CU; we held 24 deep-burst
// waves. Go shallow + steady + full occupancy):
//  - Rolling 3-row window over a 16-row chunk per thread (read amp 1.125x),
//    software-pipelined 2 rows ahead (prefetch breaks v2's serial dep chain).
//  - ~50 VGPRs; __launch_bounds__(256,8) caps at 64 VGPR -> 32 waves/CU.
//  - Per 2-row step: 2 vector loads + 4 scalar gathers in flight, 2 computes,
//    2 plain stores -> few live DRAM pages per wave, steady address stream.
//  - Compile-time-guarded tail prefetches (full unroll, r is constant).
//  - XCD-aware bijective block swizzle kept (grid 4096 % 8 == 0).

#define H_DIM 2048
#define W_DIM 2048
#define W4    (W_DIM / 4)   // 512 float4 per row
#define CH    16            // rows per thread (chunk height)
#define BLK   256           // threads per block -> half-row span

typedef float fvec4 __attribute__((ext_vector_type(4)));

__global__ __launch_bounds__(BLK, 8) void FCNN_63651415326860_kernel(
    const float* __restrict__ x,
    const float* __restrict__ a,
    const float* __restrict__ w,
    float* __restrict__ out)
{
    // ---- XCD-aware swizzle (bijective: gridDim.x = 4096, divisible by 8) ----
    const int chunk = gridDim.x >> 3;
    const int swz   = (blockIdx.x & 7) * chunk + (blockIdx.x >> 3);

    const int half = swz & 1;     // which half-row (0: cols 0..255, 1: 256..511)
    const int band = swz >> 1;    // 16-row chunk index across B*H

    const int col4  = half * BLK + (int)threadIdx.x;  // float4 column, 0..511
    const int rowg0 = band * CH;                      // first global row
    const int row0  = rowg0 & (H_DIM - 1);            // row within image
                                                      // (CH | H_DIM: no image
                                                      //  crossing in a chunk)

    const float4* __restrict__ x4 = (const float4*)x;
    const int v0 = rowg0 * W4 + col4;                 // float4 index of row 0

    const bool top = (row0 == 0);
    const bool bot = (row0 + CH == H_DIM);

    // horizontal neighbor element offsets (clamped via select, branch-free)
    const int s0   = v0 * 4;                          // max 67M, fits int
    const int offL = (col4 != 0)      ? s0 - 1 : s0;
    const int offR = (col4 != W4 - 1) ? s0 + 4 : s0 + 3;

    // broadcast scalars (uniform addresses -> s_load, cached)
    const float a0 = a[0], a1 = a[1], a2 = a[2];
    const float w0 = w[0], w1 = w[1], w2 = w[2], w3 = w[3];

    // clamp row index k (relative to chunk) at the image bottom; k is a
    // compile-time literal under full unroll, bot is block-uniform.
    #define RIDX(k) (bot ? (((k) > CH - 1) ? CH - 1 : (k)) : (k))

    #define ROW(up_, cur_, dn_, lw_, rw_, vi_)                                  \
    {                                                                           \
        fvec4 res_;                                                             \
        res_.x = a0 * (cur_).x + a1 * ((lw_)    + (cur_).y)                     \
               + a2 * ((up_).x + (dn_).x)                                       \
               + fmaf(fmaf(fmaf(w3, (cur_).x, w2), (cur_).x, w1), (cur_).x, w0);\
        res_.y = a0 * (cur_).y + a1 * ((cur_).x + (cur_).z)                     \
               + a2 * ((up_).y + (dn_).y)                                       \
               + fmaf(fmaf(fmaf(w3, (cur_).y, w2), (cur_).y, w1), (cur_).y, w0);\
        res_.z = a0 * (cur_).z + a1 * ((cur_).y + (cur_).w)                     \
               + a2 * ((up_).z + (dn_).z)                                       \
               + fmaf(fmaf(fmaf(w3, (cur_).z, w2), (cur_).z, w1), (cur_).z, w0);\
        res_.w = a0 * (cur_).w + a1 * ((cur_).z + (rw_))                        \
               + a2 * ((up_).w + (dn_).w)                                       \
               + fmaf(fmaf(fmaf(w3, (cur_).w, w2), (cur_).w, w1), (cur_).w, w0);\
        *(fvec4*)(out + (size_t)(vi_) * 4) = res_;                              \
    }

    // ---- pipeline init: window rows -1..2, gathers rows 0..1 ----
    float4 A = x4[top ? v0 : v0 - W4];      // row r-1
    float4 B = x4[v0];                      // row r
    float4 C = x4[v0 + W4];                 // row r+1
    float4 D = x4[v0 + RIDX(2) * W4];       // row r+2
    float lw0 = x[offL],          rw0 = x[offR];
    float lw1 = x[offL + W_DIM],  rw1 = x[offR + W_DIM];

    #pragma unroll
    for (int r = 0; r < CH; r += 2) {
        // prefetch 2-3 rows ahead (skipped at the tail at compile time)
        float4 E = D, F = D;
        float lw2 = lw0, rw2 = rw0, lw3 = lw0, rw3 = rw0;
        if (r + 3 <= CH)     E   = x4[v0 + RIDX(r + 3) * W4];
        if (r + 4 <= CH)     F   = x4[v0 + RIDX(r + 4) * W4];
        if (r + 2 <= CH - 1) { lw2 = x[offL + RIDX(r + 2) * W_DIM];
                               rw2 = x[offR + RIDX(r + 2) * W_DIM]; }
        if (r + 3 <= CH - 1) { lw3 = x[offL + RIDX(r + 3) * W_DIM];
                               rw3 = x[offR + RIDX(r + 3) * W_DIM]; }

        // compute rows r and r+1 while prefetches are in flight
        ROW(A, B, C, lw0, rw0, v0 + r * W4);
        ROW(B, C, D, lw1, rw1, v0 + (r + 1) * W4);

        // rotate the window
        A = C; B = D; C = E; D = F;
        lw0 = lw2; rw0 = rw2; lw1 = lw3; rw1 = rw3;
    }

    #undef ROW
    #undef RIDX
}

extern "C" void kernel_launch(void* const* d_in, const int* in_sizes, int n_in,
                              void* d_out, int out_size, void* d_ws, size_t ws_size,
                              hipStream_t stream) {
    const float* x = (const float*)d_in[0];   // 16*1*2048*2048 fp32
    const float* a = (const float*)d_in[1];   // 3 fp32
    const float* w = (const float*)d_in[2];   // 4 fp32
    float* out = (float*)d_out;

    const int total4 = out_size / 4;          // 16,777,216 float4s
    const int grid = total4 / (BLK * CH);     // 4096 blocks

    FCNN_63651415326860_kernel<<<grid, BLK, 0, stream>>>(x, a, w, out);
}